// Round 3
// baseline (595.535 us; speedup 1.0000x reference)
//
#include <hip/hip_runtime.h>
#include <hip/hip_bf16.h>
#include <stdint.h>

#define NODES 50000
#define NEDGE 800000
#define TEDGE (NEDGE + NODES)

typedef unsigned short u16;
typedef unsigned int u32;

__device__ __forceinline__ float bf2f(u16 v) {
  return __uint_as_float(((u32)v) << 16);
}
__device__ __forceinline__ u16 f2bf(float f) {
  u32 u = __float_as_uint(f);
  u32 r = (u + 0x7FFFu + ((u >> 16) & 1u)) >> 16;
  return (u16)r;
}
__device__ __forceinline__ float lrelu(float x) {
  return (x > 0.f) ? x : 0.2f * x;
}
__device__ __forceinline__ int clampn(int v) {
  return ((u32)v < NODES) ? v : 0;
}
// fb = "external float arrays are bf16"; else plain f32
__device__ __forceinline__ float load1(const void* p, size_t i, bool fb) {
  return fb ? bf2f(((const u16*)p)[i]) : ((const float*)p)[i];
}
__device__ __forceinline__ float4 load4(const void* p, size_t i, bool fb) {
  if (fb) {
    ushort4 v = *(const ushort4*)((const u16*)p + i);
    return make_float4(bf2f(v.x), bf2f(v.y), bf2f(v.z), bf2f(v.w));
  }
  return *(const float4*)((const float*)p + i);
}

// ---------------- dtype probes ----------------
// flags[0]: edge_index is int64 (odd int32 words all zero, some even nonzero)
// flags[1]: float arrays are bf16 (no garbage exponents in even u16 halves)
__global__ void k_probe(const int* __restrict__ ei, const u16* __restrict__ xs16,
                        int* __restrict__ flags) {
  if (threadIdx.x != 0 || blockIdx.x != 0) return;
  int odd_nz = 0, even_nz = 0;
  for (int i = 0; i < 64; ++i) {
    if (ei[2 * i + 1] != 0) odd_nz = 1;
    if (ei[2 * i] != 0) even_nz = 1;
  }
  flags[0] = (!odd_nz && even_nz) ? 1 : 0;
  int big = 0;
  for (int i = 0; i < 512; i += 2) {
    u32 e = (xs16[i] >> 7) & 0xFF;  // bf16-exponent field of even halves
    if (e >= 0x90) big++;           // |v| >= 2^17: impossible for N(0,1) bf16
  }
  flags[1] = (big >= 8) ? 0 : 1;
}

// ---------------- CSR build ----------------

__global__ __launch_bounds__(256) void k_hist(const int* __restrict__ ei,
                                              const int* __restrict__ flags,
                                              int* deg) {
  int e = blockIdx.x * 256 + threadIdx.x;
  if (e >= TEDGE) return;
  int d;
  if (e < NEDGE) {
    d = flags[0] ? ei[2 * (NEDGE + e)] : ei[NEDGE + e];
  } else {
    d = e - NEDGE;
  }
  atomicAdd(&deg[clampn(d)], 1);
}

__global__ __launch_bounds__(1024) void k_scan(const int* __restrict__ deg,
                                               int* __restrict__ rowptr,
                                               int* __restrict__ cursor, int n) {
  int t = threadIdx.x, lane = t & 63, w = t >> 6;
  __shared__ int swave[16], soff[17];
  int carry = 0;
  for (int base = 0; base < n; base += 4096) {
    int i0 = base + t * 4;
    int v[4];
#pragma unroll
    for (int j = 0; j < 4; j++) { int i = i0 + j; v[j] = (i < n) ? deg[i] : 0; }
    int local = v[0] + v[1] + v[2] + v[3];
    int x = local;
#pragma unroll
    for (int off = 1; off < 64; off <<= 1) {
      int y = __shfl_up(x, off);
      if (lane >= off) x += y;
    }
    if (lane == 63) swave[w] = x;
    __syncthreads();
    if (w == 0) {
      int wv = (lane < 16) ? swave[lane] : 0;
#pragma unroll
      for (int off = 1; off < 16; off <<= 1) {
        int y = __shfl_up(wv, off);
        if (lane >= off) wv += y;
      }
      if (lane < 16) soff[lane + 1] = wv;
      if (lane == 0) soff[0] = 0;
    }
    __syncthreads();
    int run = carry + soff[w] + (x - local);
#pragma unroll
    for (int j = 0; j < 4; j++) {
      int i = i0 + j;
      if (i < n) { rowptr[i] = run; cursor[i] = run; }
      run += v[j];
    }
    carry += soff[16];
    __syncthreads();
  }
  if (t == 0) rowptr[n] = carry;
}

__global__ __launch_bounds__(256) void k_scatter(const int* __restrict__ ei,
                                                 const int* __restrict__ flags,
                                                 int* cursor, int* __restrict__ srcs) {
  int e = blockIdx.x * 256 + threadIdx.x;
  if (e >= TEDGE) return;
  int d, s;
  if (e < NEDGE) {
    if (flags[0]) { s = ei[2 * e]; d = ei[2 * (NEDGE + e)]; }
    else { s = ei[e]; d = ei[NEDGE + e]; }
  } else {
    s = e - NEDGE; d = s;
  }
  int pos = atomicAdd(&cursor[clampn(d)], 1);
  srcs[pos] = clampn(s);
}

// ---------------- GEMM: h = x @ W (no bias) ----------------
// XEXT: x is an external input (dtype from runtime flag); else internal (HBF).

template <int K, int OSEG, int RPB, bool XEXT, bool HBF>
__global__ __launch_bounds__(256) void k_gemm(const void* __restrict__ xin,
                                              const void* __restrict__ Wg,
                                              void* __restrict__ hout,
                                              const int* __restrict__ flags,
                                              int n, int Otot) {
  constexpr int TPR = 256 / RPB;
  constexpr int XSTR = K + 4;
  __shared__ float ws[K * OSEG];
  __shared__ float xs[RPB * XSTR];
  int t = threadIdx.x;
  int row0 = blockIdx.x * RPB;
  int seg = blockIdx.y;
  bool fb = flags[1] != 0;

  {  // stage W -> f32 LDS
    constexpr int PER = (K * OSEG) / 256;
    int idx = t * PER;
    int k = idx / OSEG, col = idx % OSEG;
    size_t goff = (size_t)k * Otot + (size_t)seg * OSEG + col;
    float* lp = ws + k * OSEG + col;
#pragma unroll
    for (int j = 0; j < PER; j += 4)
      *(float4*)(lp + j) = load4(Wg, goff + j, fb);
  }
  {  // stage x tile -> f32 LDS
    constexpr int PERX = (RPB * K) / 256;
    int idx = t * PERX;
    int r = idx / K, col = idx % K;
    int grow = row0 + r;
    if (grow >= n) grow = n - 1;
    size_t goff = (size_t)grow * K + col;
    float* lp = xs + r * XSTR + col;
    bool xbf = XEXT ? fb : HBF;
#pragma unroll
    for (int j = 0; j < PERX; j += 4)
      *(float4*)(lp + j) = load4(xin, goff + j, xbf);
  }
  __syncthreads();

  int lr = t / TPR;
  int oc = (t % TPR) * 4;
  int row = row0 + lr;
  float4 acc = make_float4(0.f, 0.f, 0.f, 0.f);
#pragma unroll 4
  for (int k2 = 0; k2 < K; ++k2) {
    float xv = xs[lr * XSTR + k2];
    float4 wv = *(const float4*)(ws + k2 * OSEG + oc);
    acc.x += xv * wv.x; acc.y += xv * wv.y;
    acc.z += xv * wv.z; acc.w += xv * wv.w;
  }
  if (row < n) {
    size_t off = (size_t)row * Otot + (size_t)seg * OSEG + oc;
    if (HBF) {
      ushort4 o;
      o.x = f2bf(acc.x); o.y = f2bf(acc.y); o.z = f2bf(acc.z); o.w = f2bf(acc.w);
      *(ushort4*)((u16*)hout + off) = o;
    } else {
      *(float4*)((float*)hout + off) = acc;
    }
  }
}

// ---------------- attention dots ----------------

template <int H, int C, bool IBF>
__global__ __launch_bounds__(256) void k_attdot(const void* __restrict__ hbuf,
                                                const void* __restrict__ a_src,
                                                const void* __restrict__ a_dst,
                                                const int* __restrict__ flags,
                                                float* __restrict__ asg,
                                                float* __restrict__ adg, int n) {
  int id = blockIdx.x * 256 + threadIdx.x;
  if (id >= n * H) return;
  bool fb = flags[1] != 0;
  int node = id / H, h = id % H;
  size_t off = (size_t)node * (H * C) + h * C;
  float s = 0.f, d = 0.f;
#pragma unroll
  for (int c = 0; c < C; ++c) {
    float hv = load1(hbuf, off + c, IBF);
    s += hv * load1(a_src, h * C + c, fb);
    d += hv * load1(a_dst, h * C + c, fb);
  }
  asg[id] = s;
  adg[id] = d;
}

// ---------------- per-node softmax + aggregation (wave per node) ----------------
// FINAL: store dtype follows runtime flag (bf16 iff inputs were bf16), else OBFC.

template <int H, int C, bool RELU, bool IBF, bool OBFC, bool FINAL>
__global__ __launch_bounds__(256) void k_agg(const void* __restrict__ hbuf,
                                             const float* __restrict__ asg,
                                             const float* __restrict__ adg,
                                             const int* __restrict__ rowptr,
                                             const int* __restrict__ srcs,
                                             const void* __restrict__ bias,
                                             const int* __restrict__ flags,
                                             void* __restrict__ outp, int n) {
  constexpr int HC = H * C;
  constexpr int CPL = (HC == 128) ? 2 : 1;
  int lane = threadIdx.x & 63;
  int node = blockIdx.x * 4 + (threadIdx.x >> 6);
  if (node >= n) return;
  bool fb = flags[1] != 0;
  int start = rowptr[node], end = rowptr[node + 1];
  if (end < start || end - start > TEDGE) { start = 0; end = 0; }

  float adh[H];
#pragma unroll
  for (int h = 0; h < H; ++h) adh[h] = adg[node * H + h];

  // pass 1: per-head max
  float mx[H];
#pragma unroll
  for (int h = 0; h < H; ++h) mx[h] = -1e30f;
  for (int e = start + lane; e < end; e += 64) {
    int s = srcs[e]; s = clampn(s);
#pragma unroll
    for (int h = 0; h < H; ++h)
      mx[h] = fmaxf(mx[h], lrelu(asg[s * H + h] + adh[h]));
  }
#pragma unroll
  for (int off = 32; off >= 1; off >>= 1) {
#pragma unroll
    for (int h = 0; h < H; ++h) mx[h] = fmaxf(mx[h], __shfl_xor(mx[h], off));
  }

  // pass 2: denom
  float sm[H];
#pragma unroll
  for (int h = 0; h < H; ++h) sm[h] = 0.f;
  for (int e = start + lane; e < end; e += 64) {
    int s = srcs[e]; s = clampn(s);
#pragma unroll
    for (int h = 0; h < H; ++h)
      sm[h] += __expf(fminf(lrelu(asg[s * H + h] + adh[h]) - mx[h], 60.f));
  }
#pragma unroll
  for (int off = 32; off >= 1; off >>= 1) {
#pragma unroll
    for (int h = 0; h < H; ++h) sm[h] += __shfl_xor(sm[h], off);
  }
  float inv[H];
#pragma unroll
  for (int h = 0; h < H; ++h) inv[h] = 1.f / (sm[h] + 1e-16f);

  int myhead;
  if (CPL == 2) myhead = lane >> 4;
  else myhead = (lane < HC) ? (lane / C) : 0;
  bool active = (CPL == 2) || (lane < HC);

  // pass 3: weighted accumulate
  float acc0 = 0.f, acc1 = 0.f;
  for (int chunk = start; chunk < end; chunk += 64) {
    int e = chunk + lane;
    int s = 0;
    float aw[H];
#pragma unroll
    for (int h = 0; h < H; ++h) aw[h] = 0.f;
    if (e < end) {
      s = srcs[e]; s = clampn(s);
#pragma unroll
      for (int h = 0; h < H; ++h)
        aw[h] = __expf(fminf(lrelu(asg[s * H + h] + adh[h]) - mx[h], 60.f)) * inv[h];
    }
    int cn = min(64, end - chunk);
    for (int j = 0; j < cn; ++j) {
      int sj = __shfl(s, j);
      float asel;
      float a0 = __shfl(aw[0], j);
      if (H == 1) {
        asel = a0;
      } else if (H == 2) {
        float a1 = __shfl(aw[1], j);
        asel = myhead ? a1 : a0;
      } else {
        float a1 = __shfl(aw[1], j);
        float a2 = __shfl(aw[2], j);
        float a3 = __shfl(aw[3], j);
        float s01 = (myhead & 1) ? a1 : a0;
        float s23 = (myhead & 1) ? a3 : a2;
        asel = (myhead & 2) ? s23 : s01;
      }
      if (CPL == 2) {
        float2 v;
        if (IBF) {
          u32 wv = *(const u32*)((const u16*)hbuf + (size_t)sj * HC + 2 * lane);
          v = make_float2(bf2f((u16)wv), bf2f((u16)(wv >> 16)));
        } else {
          v = *(const float2*)((const float*)hbuf + (size_t)sj * HC + 2 * lane);
        }
        acc0 += asel * v.x;
        acc1 += asel * v.y;
      } else if (active) {
        float hv = load1(hbuf, (size_t)sj * HC + lane, IBF);
        acc0 += asel * hv;
      }
    }
  }

  // epilogue
  bool obf = FINAL ? fb : OBFC;
  if (CPL == 2) {
    int c0 = 2 * lane;
    float v0 = acc0 + load1(bias, c0, fb);
    float v1 = acc1 + load1(bias, c0 + 1, fb);
    if (RELU) { v0 = fmaxf(v0, 0.f); v1 = fmaxf(v1, 0.f); }
    if (obf) {
      u32 wv = (u32)f2bf(v0) | ((u32)f2bf(v1) << 16);
      *(u32*)((u16*)outp + (size_t)node * HC + c0) = wv;
    } else {
      *(float2*)((float*)outp + (size_t)node * HC + c0) = make_float2(v0, v1);
    }
  } else if (active) {
    float v = acc0 + load1(bias, lane, fb);
    if (RELU) v = fmaxf(v, 0.f);
    if (obf) ((u16*)outp)[(size_t)node * HC + lane] = f2bf(v);
    else ((float*)outp)[(size_t)node * HC + lane] = v;
  }
}

// ---------------- launch ----------------

template <bool HBF>
static void run_layers(const void* x, const void* W1, const void* as1, const void* ad1,
                       const void* b1, const void* W2, const void* as2, const void* ad2,
                       const void* b2, const void* W3, const void* as3, const void* ad3,
                       const void* b3, const int* rowptr, const int* srcs,
                       const int* flags, float* asg, float* adg, void* hbuf,
                       void* obuf, void* d_out, hipStream_t stream) {
  // layer 1: 128 -> 4x32 concat, relu
  k_gemm<128, 64, 16, true, HBF><<<dim3(NODES / 16, 2), 256, 0, stream>>>(x, W1, hbuf, flags, NODES, 128);
  k_attdot<4, 32, HBF><<<(NODES * 4 + 255) / 256, 256, 0, stream>>>(hbuf, as1, ad1, flags, asg, adg, NODES);
  k_agg<4, 32, true, HBF, HBF, false><<<(NODES + 3) / 4, 256, 0, stream>>>(hbuf, asg, adg, rowptr, srcs, b1, flags, obuf, NODES);
  // layer 2: 128 -> 2x32 concat, relu
  k_gemm<128, 64, 16, false, HBF><<<dim3(NODES / 16, 1), 256, 0, stream>>>(obuf, W2, hbuf, flags, NODES, 64);
  k_attdot<2, 32, HBF><<<(NODES * 2 + 255) / 256, 256, 0, stream>>>(hbuf, as2, ad2, flags, asg, adg, NODES);
  k_agg<2, 32, true, HBF, HBF, false><<<(NODES + 3) / 4, 256, 0, stream>>>(hbuf, asg, adg, rowptr, srcs, b2, flags, obuf, NODES);
  // layer 3: 64 -> 1x16 mean(=identity), out dtype follows input dtype
  k_gemm<64, 16, 64, false, HBF><<<dim3((NODES + 63) / 64, 1), 256, 0, stream>>>(obuf, W3, hbuf, flags, NODES, 16);
  k_attdot<1, 16, HBF><<<(NODES + 255) / 256, 256, 0, stream>>>(hbuf, as3, ad3, flags, asg, adg, NODES);
  k_agg<1, 16, false, HBF, false, true><<<(NODES + 3) / 4, 256, 0, stream>>>(hbuf, asg, adg, rowptr, srcs, b3, flags, d_out, NODES);
}

extern "C" void kernel_launch(void* const* d_in, const int* in_sizes, int n_in,
                              void* d_out, int out_size, void* d_ws, size_t ws_size,
                              hipStream_t stream) {
  const void* x   = d_in[0];
  const int* ei   = (const int*)d_in[1];
  const void* W1  = d_in[2];
  const void* as1 = d_in[3];
  const void* ad1 = d_in[4];
  const void* b1  = d_in[5];
  const void* W2  = d_in[6];
  const void* as2 = d_in[7];
  const void* ad2 = d_in[8];
  const void* b2  = d_in[9];
  const void* W3  = d_in[10];
  const void* as3 = d_in[11];
  const void* ad3 = d_in[12];
  const void* b3  = d_in[13];

  char* w = (char*)d_ws;
  auto alloc = [&](size_t bytes) {
    char* p = w;
    w += (bytes + 255) & ~(size_t)255;
    return p;
  };
  int* flags    = (int*)alloc(256);
  int* deg      = (int*)alloc((size_t)NODES * 4);
  int* cursor   = (int*)alloc((size_t)NODES * 4);
  int* rowptr   = (int*)alloc((size_t)(NODES + 1) * 4);
  int* srcs     = (int*)alloc((size_t)TEDGE * 4);
  float* asg    = (float*)alloc((size_t)NODES * 4 * 4);
  float* adg    = (float*)alloc((size_t)NODES * 4 * 4);
  size_t small_used = (size_t)(w - (char*)d_ws);
  size_t f32_need = small_used + 2 * (((size_t)NODES * 128 * 4 + 255) & ~(size_t)255);
  bool use_f32 = (ws_size >= f32_need);
  size_t helem = use_f32 ? 4 : 2;
  void* hbuf = alloc((size_t)NODES * 128 * helem);
  void* obuf = alloc((size_t)NODES * 128 * helem);

  // probes + CSR build (graph shared by all 3 layers)
  k_probe<<<1, 64, 0, stream>>>(ei, (const u16*)x, flags);
  hipMemsetAsync(deg, 0, (size_t)NODES * 4, stream);
  k_hist<<<(TEDGE + 255) / 256, 256, 0, stream>>>(ei, flags, deg);
  k_scan<<<1, 1024, 0, stream>>>(deg, rowptr, cursor, NODES);
  k_scatter<<<(TEDGE + 255) / 256, 256, 0, stream>>>(ei, flags, cursor, srcs);

  if (use_f32) {
    run_layers<false>(x, W1, as1, ad1, b1, W2, as2, ad2, b2, W3, as3, ad3, b3,
                      rowptr, srcs, flags, asg, adg, hbuf, obuf, d_out, stream);
  } else {
    run_layers<true>(x, W1, as1, ad1, b1, W2, as2, ad2, b2, W3, as3, ad3, b3,
                     rowptr, srcs, flags, asg, adg, hbuf, obuf, d_out, stream);
  }
}

// Round 4
// 464.365 us; speedup vs baseline: 1.2825x; 1.2825x over previous
//
#include <hip/hip_runtime.h>
#include <hip/hip_bf16.h>
#include <stdint.h>

#define NODES 50000
#define NEDGE 800000
#define TEDGE (NEDGE + NODES)

typedef unsigned short u16;
typedef unsigned int u32;
typedef unsigned long long u64;

__device__ __forceinline__ float bf2f(u16 v) {
  return __uint_as_float(((u32)v) << 16);
}
__device__ __forceinline__ u16 f2bf(float f) {
  u32 u = __float_as_uint(f);
  u32 r = (u + 0x7FFFu + ((u >> 16) & 1u)) >> 16;
  return (u16)r;
}
__device__ __forceinline__ float lrelu(float x) {
  return (x > 0.f) ? x : 0.2f * x;
}
__device__ __forceinline__ int clampn(int v) {
  return ((u32)v < NODES) ? v : 0;
}
// fb = "external float arrays are bf16"; else plain f32
__device__ __forceinline__ float load1(const void* p, size_t i, bool fb) {
  return fb ? bf2f(((const u16*)p)[i]) : ((const float*)p)[i];
}
__device__ __forceinline__ float4 load4(const void* p, size_t i, bool fb) {
  if (fb) {
    ushort4 v = *(const ushort4*)((const u16*)p + i);
    return make_float4(bf2f(v.x), bf2f(v.y), bf2f(v.z), bf2f(v.w));
  }
  return *(const float4*)((const float*)p + i);
}
__device__ __forceinline__ float bflo(u32 w) { return __uint_as_float(w << 16); }
__device__ __forceinline__ float bfhi(u32 w) { return __uint_as_float(w & 0xFFFF0000u); }

// ---------------- probes + deg zero ----------------
// flags[0]: edge_index is int64; flags[1]: float arrays are bf16
__global__ __launch_bounds__(256) void k_probe(const int* __restrict__ ei,
                                               const u16* __restrict__ xs16,
                                               int* __restrict__ flags,
                                               int* __restrict__ deg) {
  int t = threadIdx.x;
  int g = blockIdx.x * 256 + t;
  if (g < NODES) deg[g] = 0;
  if (blockIdx.x == 0 && t < 64) {
    int odd = 0, even = 0, big = 0;
#pragma unroll
    for (int k = 0; k < 4; ++k) {
      int idx = t + 64 * k;
      odd |= (ei[2 * idx + 1] != 0);
      even |= (ei[2 * idx] != 0);
      u32 ex = (xs16[2 * (t * 4 + k)] >> 7) & 0xFF;
      big += (ex >= 0x90);  // |v| >= 2^17: impossible for N(0,1) bf16
    }
    u64 bo = __ballot(odd);
    u64 be = __ballot(even);
#pragma unroll
    for (int off = 32; off >= 1; off >>= 1) big += __shfl_xor(big, off);
    if (t == 0) {
      flags[0] = (bo == 0ull && be != 0ull) ? 1 : 0;
      flags[1] = (big >= 8) ? 0 : 1;
    }
  }
}

// ---------------- CSR build ----------------

__global__ __launch_bounds__(256) void k_hist(const int* __restrict__ ei,
                                              const int* __restrict__ flags,
                                              int* deg) {
  int e = blockIdx.x * 256 + threadIdx.x;
  if (e >= TEDGE) return;
  int d;
  if (e < NEDGE) {
    d = flags[0] ? ei[2 * (NEDGE + e)] : ei[NEDGE + e];
  } else {
    d = e - NEDGE;
  }
  atomicAdd(&deg[clampn(d)], 1);
}

__global__ __launch_bounds__(1024) void k_scan(const int* __restrict__ deg,
                                               int* __restrict__ rowptr,
                                               int* __restrict__ cursor, int n) {
  int t = threadIdx.x, lane = t & 63, w = t >> 6;
  __shared__ int swave[16], soff[17];
  int carry = 0;
  for (int base = 0; base < n; base += 4096) {
    int i0 = base + t * 4;
    int v[4];
#pragma unroll
    for (int j = 0; j < 4; j++) { int i = i0 + j; v[j] = (i < n) ? deg[i] : 0; }
    int local = v[0] + v[1] + v[2] + v[3];
    int x = local;
#pragma unroll
    for (int off = 1; off < 64; off <<= 1) {
      int y = __shfl_up(x, off);
      if (lane >= off) x += y;
    }
    if (lane == 63) swave[w] = x;
    __syncthreads();
    if (w == 0) {
      int wv = (lane < 16) ? swave[lane] : 0;
#pragma unroll
      for (int off = 1; off < 16; off <<= 1) {
        int y = __shfl_up(wv, off);
        if (lane >= off) wv += y;
      }
      if (lane < 16) soff[lane + 1] = wv;
      if (lane == 0) soff[0] = 0;
    }
    __syncthreads();
    int run = carry + soff[w] + (x - local);
#pragma unroll
    for (int j = 0; j < 4; j++) {
      int i = i0 + j;
      if (i < n) { rowptr[i] = run; cursor[i] = run; }
      run += v[j];
    }
    carry += soff[16];
    __syncthreads();
  }
  if (t == 0) rowptr[n] = carry;
}

__global__ __launch_bounds__(256) void k_scatter(const int* __restrict__ ei,
                                                 const int* __restrict__ flags,
                                                 int* cursor, int* __restrict__ srcs) {
  int e = blockIdx.x * 256 + threadIdx.x;
  if (e >= TEDGE) return;
  int d, s;
  if (e < NEDGE) {
    if (flags[0]) { s = ei[2 * e]; d = ei[2 * (NEDGE + e)]; }
    else { s = ei[e]; d = ei[NEDGE + e]; }
  } else {
    s = e - NEDGE; d = s;
  }
  int pos = atomicAdd(&cursor[clampn(d)], 1);
  srcs[pos] = clampn(s);
}

// ---------------- GEMM: h = x @ W -> bf16 out ----------------
// XEXT: x is an external input (dtype via runtime flag); else internal bf16.

template <int K, int OSEG, int RPB, bool XEXT>
__global__ __launch_bounds__(256) void k_gemm(const void* __restrict__ xin,
                                              const void* __restrict__ Wg,
                                              u16* __restrict__ hout,
                                              const int* __restrict__ flags,
                                              int n, int Otot) {
  constexpr int TPR = 256 / RPB;
  constexpr int XSTR = K + 4;
  __shared__ float ws[K * OSEG];
  __shared__ float xs[RPB * XSTR];
  int t = threadIdx.x;
  int row0 = blockIdx.x * RPB;
  int seg = blockIdx.y;
  bool fb = flags[1] != 0;

  {  // stage W -> f32 LDS
    constexpr int PER = (K * OSEG) / 256;
    int idx = t * PER;
    int k = idx / OSEG, col = idx % OSEG;
    size_t goff = (size_t)k * Otot + (size_t)seg * OSEG + col;
    float* lp = ws + k * OSEG + col;
#pragma unroll
    for (int j = 0; j < PER; j += 4)
      *(float4*)(lp + j) = load4(Wg, goff + j, fb);
  }
  {  // stage x tile -> f32 LDS
    constexpr int PERX = (RPB * K) / 256;
    int idx = t * PERX;
    int r = idx / K, col = idx % K;
    int grow = row0 + r;
    if (grow >= n) grow = n - 1;
    size_t goff = (size_t)grow * K + col;
    float* lp = xs + r * XSTR + col;
    bool xbf = XEXT ? fb : true;
#pragma unroll
    for (int j = 0; j < PERX; j += 4)
      *(float4*)(lp + j) = load4(xin, goff + j, xbf);
  }
  __syncthreads();

  int lr = t / TPR;
  int oc = (t % TPR) * 4;
  int row = row0 + lr;
  float4 acc = make_float4(0.f, 0.f, 0.f, 0.f);
#pragma unroll 4
  for (int k2 = 0; k2 < K; ++k2) {
    float xv = xs[lr * XSTR + k2];
    float4 wv = *(const float4*)(ws + k2 * OSEG + oc);
    acc.x += xv * wv.x; acc.y += xv * wv.y;
    acc.z += xv * wv.z; acc.w += xv * wv.w;
  }
  if (row < n) {
    size_t off = (size_t)row * Otot + (size_t)seg * OSEG + oc;
    ushort4 o;
    o.x = f2bf(acc.x); o.y = f2bf(acc.y); o.z = f2bf(acc.z); o.w = f2bf(acc.w);
    *(ushort4*)(hout + off) = o;
  }
}

// ---------------- attention dots (bf16 h) ----------------

template <int H, int C>
__global__ __launch_bounds__(256) void k_attdot(const u16* __restrict__ hbuf,
                                                const void* __restrict__ a_src,
                                                const void* __restrict__ a_dst,
                                                const int* __restrict__ flags,
                                                float* __restrict__ asg,
                                                float* __restrict__ adg, int n) {
  int id = blockIdx.x * 256 + threadIdx.x;
  if (id >= n * H) return;
  bool fb = flags[1] != 0;
  int node = id / H, h = id % H;
  const u16* hp = hbuf + (size_t)node * (H * C) + h * C;
  float s = 0.f, d = 0.f;
#pragma unroll
  for (int c = 0; c < C; c += 4) {
    ushort4 v = *(const ushort4*)(hp + c);
    float f0 = bf2f(v.x), f1 = bf2f(v.y), f2 = bf2f(v.z), f3 = bf2f(v.w);
    s += f0 * load1(a_src, h * C + c + 0, fb) + f1 * load1(a_src, h * C + c + 1, fb)
       + f2 * load1(a_src, h * C + c + 2, fb) + f3 * load1(a_src, h * C + c + 3, fb);
    d += f0 * load1(a_dst, h * C + c + 0, fb) + f1 * load1(a_dst, h * C + c + 1, fb)
       + f2 * load1(a_dst, h * C + c + 2, fb) + f3 * load1(a_dst, h * C + c + 3, fb);
  }
  asg[id] = s;
  adg[id] = d;
}

// ---------------- per-node softmax + aggregation (wave per node, bf16 h) ----

template <int H, int C, bool RELU, bool FINAL>
__global__ __launch_bounds__(256) void k_agg(const u16* __restrict__ hbuf,
                                             const float* __restrict__ asg,
                                             const float* __restrict__ adg,
                                             const int* __restrict__ rowptr,
                                             const int* __restrict__ srcs,
                                             const void* __restrict__ bias,
                                             const int* __restrict__ flags,
                                             void* __restrict__ outp, int n) {
  constexpr int HC = H * C;
  constexpr int CPL = (HC == 128) ? 2 : 1;
  __shared__ int lds_s[4][64];
  __shared__ float lds_a[4][64][H];
  int lane = threadIdx.x & 63;
  int w = threadIdx.x >> 6;
  int node = blockIdx.x * 4 + w;
  if (node >= n) return;
  bool fb = flags[1] != 0;
  int start = rowptr[node], end = rowptr[node + 1];
  if (end < start || end - start > TEDGE) { start = 0; end = 0; }

  float adh[H];
#pragma unroll
  for (int h = 0; h < H; ++h) adh[h] = adg[node * H + h];

  // pass 1: per-head max
  float mx[H];
#pragma unroll
  for (int h = 0; h < H; ++h) mx[h] = -1e30f;
  for (int e = start + lane; e < end; e += 64) {
    int s = srcs[e];
    float av[H];
    if (H == 4) { float4 t4 = *(const float4*)(asg + s * 4);
      av[0] = t4.x; av[1] = t4.y; av[H > 2 ? 2 : 0] = t4.z; av[H > 3 ? 3 : 0] = t4.w; }
    else if (H == 2) { float2 t2 = *(const float2*)(asg + s * 2); av[0] = t2.x; av[1] = t2.y; }
    else av[0] = asg[s];
#pragma unroll
    for (int h = 0; h < H; ++h)
      mx[h] = fmaxf(mx[h], lrelu(av[h] + adh[h]));
  }
#pragma unroll
  for (int off = 32; off >= 1; off >>= 1) {
#pragma unroll
    for (int h = 0; h < H; ++h) mx[h] = fmaxf(mx[h], __shfl_xor(mx[h], off));
  }

  // pass 2: denom
  float sm[H];
#pragma unroll
  for (int h = 0; h < H; ++h) sm[h] = 0.f;
  for (int e = start + lane; e < end; e += 64) {
    int s = srcs[e];
    float av[H];
    if (H == 4) { float4 t4 = *(const float4*)(asg + s * 4);
      av[0] = t4.x; av[1] = t4.y; av[H > 2 ? 2 : 0] = t4.z; av[H > 3 ? 3 : 0] = t4.w; }
    else if (H == 2) { float2 t2 = *(const float2*)(asg + s * 2); av[0] = t2.x; av[1] = t2.y; }
    else av[0] = asg[s];
#pragma unroll
    for (int h = 0; h < H; ++h)
      sm[h] += __expf(fminf(lrelu(av[h] + adh[h]) - mx[h], 60.f));
  }
#pragma unroll
  for (int off = 32; off >= 1; off >>= 1) {
#pragma unroll
    for (int h = 0; h < H; ++h) sm[h] += __shfl_xor(sm[h], off);
  }
  float inv[H];
#pragma unroll
  for (int h = 0; h < H; ++h) inv[h] = 1.f / (sm[h] + 1e-16f);

  int myhead;
  if (CPL == 2) myhead = lane >> 4;                 // 2 ch/lane, C=32
  else if (H == 2) myhead = lane >> 5;              // 1 ch/lane, C=32
  else myhead = 0;
  bool active = (CPL == 2) || (lane < HC);

  // pass 3: stage src+alpha in wave-private LDS, 4x-unrolled gather
  float accA0 = 0.f, accA1 = 0.f, accB0 = 0.f, accB1 = 0.f;
  for (int chunk = start; chunk < end; chunk += 64) {
    int e = chunk + lane;
    int s = 0;
    float aw[H];
#pragma unroll
    for (int h = 0; h < H; ++h) aw[h] = 0.f;
    if (e < end) {
      s = srcs[e];
      float av[H];
      if (H == 4) { float4 t4 = *(const float4*)(asg + s * 4);
        av[0] = t4.x; av[1] = t4.y; av[H > 2 ? 2 : 0] = t4.z; av[H > 3 ? 3 : 0] = t4.w; }
      else if (H == 2) { float2 t2 = *(const float2*)(asg + s * 2); av[0] = t2.x; av[1] = t2.y; }
      else av[0] = asg[s];
#pragma unroll
      for (int h = 0; h < H; ++h)
        aw[h] = __expf(fminf(lrelu(av[h] + adh[h]) - mx[h], 60.f)) * inv[h];
    }
    __builtin_amdgcn_wave_barrier();  // prior reads done before overwrite
    lds_s[w][lane] = s;
#pragma unroll
    for (int h = 0; h < H; ++h) lds_a[w][lane][h] = aw[h];
    __builtin_amdgcn_wave_barrier();

    int cn = min(64, end - chunk);
    for (int j = 0; j < cn; j += 4) {  // arrays zero-padded: overrun is harmless
      int s0 = lds_s[w][j + 0], s1 = lds_s[w][j + 1];
      int s2 = lds_s[w][j + 2], s3 = lds_s[w][j + 3];
      float A0 = lds_a[w][j + 0][myhead], A1 = lds_a[w][j + 1][myhead];
      float A2 = lds_a[w][j + 2][myhead], A3 = lds_a[w][j + 3][myhead];
      if (CPL == 2) {
        u32 w0 = *(const u32*)(hbuf + (size_t)s0 * HC + 2 * lane);
        u32 w1 = *(const u32*)(hbuf + (size_t)s1 * HC + 2 * lane);
        u32 w2 = *(const u32*)(hbuf + (size_t)s2 * HC + 2 * lane);
        u32 w3 = *(const u32*)(hbuf + (size_t)s3 * HC + 2 * lane);
        accA0 += A0 * bflo(w0); accA1 += A0 * bfhi(w0);
        accB0 += A1 * bflo(w1); accB1 += A1 * bfhi(w1);
        accA0 += A2 * bflo(w2); accA1 += A2 * bfhi(w2);
        accB0 += A3 * bflo(w3); accB1 += A3 * bfhi(w3);
      } else if (active) {
        float v0 = bf2f(hbuf[(size_t)s0 * HC + lane]);
        float v1 = bf2f(hbuf[(size_t)s1 * HC + lane]);
        float v2 = bf2f(hbuf[(size_t)s2 * HC + lane]);
        float v3 = bf2f(hbuf[(size_t)s3 * HC + lane]);
        accA0 += A0 * v0; accB0 += A1 * v1;
        accA0 += A2 * v2; accB0 += A3 * v3;
      }
    }
  }
  float acc0 = accA0 + accB0, acc1 = accA1 + accB1;

  // epilogue
  bool obf = FINAL ? fb : true;
  if (CPL == 2) {
    int c0 = 2 * lane;
    float v0 = acc0 + load1(bias, c0, fb);
    float v1 = acc1 + load1(bias, c0 + 1, fb);
    if (RELU) { v0 = fmaxf(v0, 0.f); v1 = fmaxf(v1, 0.f); }
    u32 wv = (u32)f2bf(v0) | ((u32)f2bf(v1) << 16);
    *(u32*)((u16*)outp + (size_t)node * HC + c0) = wv;
  } else if (active) {
    float v = acc0 + load1(bias, lane, fb);
    if (RELU) v = fmaxf(v, 0.f);
    if (obf) ((u16*)outp)[(size_t)node * HC + lane] = f2bf(v);
    else ((float*)outp)[(size_t)node * HC + lane] = v;
  }
}

// ---------------- launch ----------------

extern "C" void kernel_launch(void* const* d_in, const int* in_sizes, int n_in,
                              void* d_out, int out_size, void* d_ws, size_t ws_size,
                              hipStream_t stream) {
  const void* x   = d_in[0];
  const int* ei   = (const int*)d_in[1];
  const void* W1  = d_in[2];
  const void* as1 = d_in[3];
  const void* ad1 = d_in[4];
  const void* b1  = d_in[5];
  const void* W2  = d_in[6];
  const void* as2 = d_in[7];
  const void* ad2 = d_in[8];
  const void* b2  = d_in[9];
  const void* W3  = d_in[10];
  const void* as3 = d_in[11];
  const void* ad3 = d_in[12];
  const void* b3  = d_in[13];

  char* w = (char*)d_ws;
  auto alloc = [&](size_t bytes) {
    char* p = w;
    w += (bytes + 255) & ~(size_t)255;
    return p;
  };
  int* flags    = (int*)alloc(256);
  int* deg      = (int*)alloc((size_t)NODES * 4);
  int* cursor   = (int*)alloc((size_t)NODES * 4);
  int* rowptr   = (int*)alloc((size_t)(NODES + 1) * 4);
  int* srcs     = (int*)alloc((size_t)TEDGE * 4);
  float* asg    = (float*)alloc((size_t)NODES * 4 * 4);
  float* adg    = (float*)alloc((size_t)NODES * 4 * 4);
  u16* hbuf     = (u16*)alloc((size_t)NODES * 128 * 2);
  u16* obuf     = (u16*)alloc((size_t)NODES * 128 * 2);

  // probes + deg zero + CSR build (graph shared by all 3 layers)
  k_probe<<<(NODES + 255) / 256, 256, 0, stream>>>(ei, (const u16*)x, flags, deg);
  k_hist<<<(TEDGE + 255) / 256, 256, 0, stream>>>(ei, flags, deg);
  k_scan<<<1, 1024, 0, stream>>>(deg, rowptr, cursor, NODES);
  k_scatter<<<(TEDGE + 255) / 256, 256, 0, stream>>>(ei, flags, cursor, srcs);

  // layer 1: 128 -> 4x32 concat, relu
  k_gemm<128, 64, 16, true><<<dim3(NODES / 16, 2), 256, 0, stream>>>(x, W1, hbuf, flags, NODES, 128);
  k_attdot<4, 32><<<(NODES * 4 + 255) / 256, 256, 0, stream>>>(hbuf, as1, ad1, flags, asg, adg, NODES);
  k_agg<4, 32, true, false><<<(NODES + 3) / 4, 256, 0, stream>>>(hbuf, asg, adg, rowptr, srcs, b1, flags, obuf, NODES);
  // layer 2: 128 -> 2x32 concat, relu
  k_gemm<128, 64, 16, false><<<dim3(NODES / 16, 1), 256, 0, stream>>>(obuf, W2, hbuf, flags, NODES, 64);
  k_attdot<2, 32><<<(NODES * 2 + 255) / 256, 256, 0, stream>>>(hbuf, as2, ad2, flags, asg, adg, NODES);
  k_agg<2, 32, true, false><<<(NODES + 3) / 4, 256, 0, stream>>>(hbuf, asg, adg, rowptr, srcs, b2, flags, obuf, NODES);
  // layer 3: 64 -> 1x16 mean(=identity), out dtype follows input dtype
  k_gemm<64, 16, 64, false><<<dim3((NODES + 63) / 64, 1), 256, 0, stream>>>(obuf, W3, hbuf, flags, NODES, 16);
  k_attdot<1, 16><<<(NODES + 255) / 256, 256, 0, stream>>>(hbuf, as3, ad3, flags, asg, adg, NODES);
  k_agg<1, 16, false, true><<<(NODES + 3) / 4, 256, 0, stream>>>(hbuf, asg, adg, rowptr, srcs, b3, flags, d_out, NODES);
}

// Round 5
// 402.387 us; speedup vs baseline: 1.4800x; 1.1540x over previous
//
#include <hip/hip_runtime.h>
#include <hip/hip_bf16.h>
#include <stdint.h>

#define NODES 50000
#define NEDGE 800000
#define TEDGE (NEDGE + NODES)

typedef unsigned short u16;
typedef unsigned int u32;
typedef unsigned long long u64;
typedef short s16x8 __attribute__((ext_vector_type(8)));
typedef float f32x4 __attribute__((ext_vector_type(4)));

__device__ __forceinline__ float bf2f(u16 v) {
  return __uint_as_float(((u32)v) << 16);
}
__device__ __forceinline__ u16 f2bf(float f) {
  u32 u = __float_as_uint(f);
  u32 r = (u + 0x7FFFu + ((u >> 16) & 1u)) >> 16;
  return (u16)r;
}
__device__ __forceinline__ float lrelu(float x) {
  return (x > 0.f) ? x : 0.2f * x;
}
__device__ __forceinline__ int clampn(int v) {
  return ((u32)v < NODES) ? v : 0;
}
// fb = "external float arrays are bf16"; else plain f32
__device__ __forceinline__ float load1(const void* p, size_t i, bool fb) {
  return fb ? bf2f(((const u16*)p)[i]) : ((const float*)p)[i];
}
__device__ __forceinline__ float bflo(u32 w) { return __uint_as_float(w << 16); }
__device__ __forceinline__ float bfhi(u32 w) { return __uint_as_float(w & 0xFFFF0000u); }

// ---------------- probes + deg zero ----------------
// flags[0]: edge_index is int64; flags[1]: float arrays are bf16
__global__ __launch_bounds__(256) void k_probe(const int* __restrict__ ei,
                                               const u16* __restrict__ xs16,
                                               int* __restrict__ flags,
                                               int* __restrict__ deg) {
  int t = threadIdx.x;
  int g = blockIdx.x * 256 + t;
  if (g < NODES) deg[g] = 0;
  if (blockIdx.x == 0 && t < 64) {
    int odd = 0, even = 0, big = 0;
#pragma unroll
    for (int k = 0; k < 4; ++k) {
      int idx = t + 64 * k;
      odd |= (ei[2 * idx + 1] != 0);
      even |= (ei[2 * idx] != 0);
      u32 ex = (xs16[2 * (t * 4 + k)] >> 7) & 0xFF;
      big += (ex >= 0x90);  // |v| >= 2^17: impossible for N(0,1) bf16
    }
    u64 bo = __ballot(odd);
    u64 be = __ballot(even);
#pragma unroll
    for (int off = 32; off >= 1; off >>= 1) big += __shfl_xor(big, off);
    if (t == 0) {
      flags[0] = (bo == 0ull && be != 0ull) ? 1 : 0;
      flags[1] = (big >= 8) ? 0 : 1;
    }
  }
}

// ---------------- W transpose: Wt[n][k] = W[k][n], bf16 out ----------------
__global__ __launch_bounds__(256) void k_tw(const void* __restrict__ W1,
                                            const void* __restrict__ W2,
                                            const void* __restrict__ W3,
                                            const int* __restrict__ flags,
                                            u16* __restrict__ wt1,
                                            u16* __restrict__ wt2,
                                            u16* __restrict__ wt3) {
  int id = blockIdx.x * 256 + threadIdx.x;
  bool fb = flags[1] != 0;
  if (id < 16384) {                       // W1: 128(K) x 128(N)
    int n = id >> 7, k = id & 127;
    wt1[n * 128 + k] = f2bf(load1(W1, (size_t)k * 128 + n, fb));
  } else if (id < 24576) {                // W2: 128(K) x 64(N)
    int r = id - 16384;
    int n = r >> 7, k = r & 127;
    wt2[n * 128 + k] = f2bf(load1(W2, (size_t)k * 64 + n, fb));
  } else if (id < 25600) {                // W3: 64(K) x 16(N)
    int r = id - 24576;
    int n = r >> 6, k = r & 63;
    wt3[n * 64 + k] = f2bf(load1(W3, (size_t)k * 16 + n, fb));
  }
}

// ---------------- CSR build ----------------

__global__ __launch_bounds__(256) void k_hist(const int* __restrict__ ei,
                                              const int* __restrict__ flags,
                                              int* deg) {
  int e = blockIdx.x * 256 + threadIdx.x;
  if (e >= TEDGE) return;
  int d;
  if (e < NEDGE) {
    d = flags[0] ? ei[2 * (NEDGE + e)] : ei[NEDGE + e];
  } else {
    d = e - NEDGE;
  }
  atomicAdd(&deg[clampn(d)], 1);
}

__global__ __launch_bounds__(1024) void k_scan(const int* __restrict__ deg,
                                               int* __restrict__ rowptr,
                                               int* __restrict__ cursor, int n) {
  int t = threadIdx.x, lane = t & 63, w = t >> 6;
  __shared__ int swave[16], soff[17];
  int carry = 0;
  for (int base = 0; base < n; base += 4096) {
    int i0 = base + t * 4;
    int v[4];
#pragma unroll
    for (int j = 0; j < 4; j++) { int i = i0 + j; v[j] = (i < n) ? deg[i] : 0; }
    int local = v[0] + v[1] + v[2] + v[3];
    int x = local;
#pragma unroll
    for (int off = 1; off < 64; off <<= 1) {
      int y = __shfl_up(x, off);
      if (lane >= off) x += y;
    }
    if (lane == 63) swave[w] = x;
    __syncthreads();
    if (w == 0) {
      int wv = (lane < 16) ? swave[lane] : 0;
#pragma unroll
      for (int off = 1; off < 16; off <<= 1) {
        int y = __shfl_up(wv, off);
        if (lane >= off) wv += y;
      }
      if (lane < 16) soff[lane + 1] = wv;
      if (lane == 0) soff[0] = 0;
    }
    __syncthreads();
    int run = carry + soff[w] + (x - local);
#pragma unroll
    for (int j = 0; j < 4; j++) {
      int i = i0 + j;
      if (i < n) { rowptr[i] = run; cursor[i] = run; }
      run += v[j];
    }
    carry += soff[16];
    __syncthreads();
  }
  if (t == 0) rowptr[n] = carry;
}

__global__ __launch_bounds__(256) void k_scatter(const int* __restrict__ ei,
                                                 const int* __restrict__ flags,
                                                 int* cursor, int* __restrict__ srcs) {
  int e = blockIdx.x * 256 + threadIdx.x;
  if (e >= TEDGE) return;
  int d, s;
  if (e < NEDGE) {
    if (flags[0]) { s = ei[2 * e]; d = ei[2 * (NEDGE + e)]; }
    else { s = ei[e]; d = ei[NEDGE + e]; }
  } else {
    s = e - NEDGE; d = s;
  }
  int pos = atomicAdd(&cursor[clampn(d)], 1);
  srcs[pos] = clampn(s);
}

// ---------------- MFMA GEMM: h[M,N] = x[M,K] @ W[K,N], bf16 in/out ----------
// Wt is pre-transposed [N][K]. 64 rows per block, wave w handles rows w*16..+15.
// Fragment maps (verified): A[m=lane&15][k=quad*8+j]; B[k=quad*8+j][n=lane&15];
// D[row=quad*4+reg][col=lane&15].

template <int K, int N, bool XEXT>
__global__ __launch_bounds__(256) void k_gmfma(const void* __restrict__ xin,
                                               const u16* __restrict__ wtg,
                                               u16* __restrict__ hout,
                                               const int* __restrict__ flags,
                                               int M) {
  constexpr int KP = K + 8;       // +8 bf16 pad: fragment reads 2-way only
  constexpr int NT = N / 16;
  constexpr int KG = K / 8;
  __shared__ u16 wlds[N * KP];
  __shared__ u16 xlds[64 * KP];
  int t = threadIdx.x;
  int row0 = blockIdx.x * 64;
  bool fb = flags[1] != 0;

  for (int i = t; i < N * KG; i += 256) {  // stage W^T (16B groups)
    int n = i / KG, kg = i % KG;
    *(uint4*)&wlds[n * KP + kg * 8] = *(const uint4*)(wtg + (size_t)n * K + kg * 8);
  }
  bool xbf = XEXT ? fb : true;
  for (int i = t; i < 64 * KG; i += 256) {  // stage x rows
    int r = i / KG, kg = i % KG;
    int grow = row0 + r;
    if (grow >= M) grow = M - 1;
    if (xbf) {
      *(uint4*)&xlds[r * KP + kg * 8] =
          *(const uint4*)((const u16*)xin + (size_t)grow * K + kg * 8);
    } else {
      const float* gp = (const float*)xin + (size_t)grow * K + kg * 8;
      float4 f0 = *(const float4*)gp, f1 = *(const float4*)(gp + 4);
      *(ushort4*)&xlds[r * KP + kg * 8] =
          make_ushort4(f2bf(f0.x), f2bf(f0.y), f2bf(f0.z), f2bf(f0.w));
      *(ushort4*)&xlds[r * KP + kg * 8 + 4] =
          make_ushort4(f2bf(f1.x), f2bf(f1.y), f2bf(f1.z), f2bf(f1.w));
    }
  }
  __syncthreads();

  int lane = t & 63, w = t >> 6;
  int lrow = lane & 15, quad = lane >> 4;
  f32x4 acc[NT];
#pragma unroll
  for (int nt = 0; nt < NT; ++nt) acc[nt] = (f32x4){0.f, 0.f, 0.f, 0.f};

  const u16* xbase = xlds + (w * 16 + lrow) * KP + quad * 8;
  const u16* wbase = wlds + lrow * KP + quad * 8;
#pragma unroll
  for (int ks = 0; ks < K / 32; ++ks) {
    s16x8 a = *(const s16x8*)(xbase + ks * 32);
#pragma unroll
    for (int nt = 0; nt < NT; ++nt) {
      s16x8 b = *(const s16x8*)(wbase + (size_t)nt * 16 * KP + ks * 32);
      acc[nt] = __builtin_amdgcn_mfma_f32_16x16x32_bf16(a, b, acc[nt], 0, 0, 0);
    }
  }

  int baserow = row0 + w * 16 + quad * 4;
#pragma unroll
  for (int nt = 0; nt < NT; ++nt) {
#pragma unroll
    for (int r = 0; r < 4; ++r) {
      int grow = baserow + r;
      if (grow < M)
        hout[(size_t)grow * N + nt * 16 + lrow] = f2bf(acc[nt][r]);
    }
  }
}

// ---------------- attention dots (bf16 h) ----------------

template <int H, int C>
__global__ __launch_bounds__(256) void k_attdot(const u16* __restrict__ hbuf,
                                                const void* __restrict__ a_src,
                                                const void* __restrict__ a_dst,
                                                const int* __restrict__ flags,
                                                float* __restrict__ asg,
                                                float* __restrict__ adg, int n) {
  int id = blockIdx.x * 256 + threadIdx.x;
  if (id >= n * H) return;
  bool fb = flags[1] != 0;
  int node = id / H, h = id % H;
  const u16* hp = hbuf + (size_t)node * (H * C) + h * C;
  float s = 0.f, d = 0.f;
#pragma unroll
  for (int c = 0; c < C; c += 4) {
    ushort4 v = *(const ushort4*)(hp + c);
    float f0 = bf2f(v.x), f1 = bf2f(v.y), f2 = bf2f(v.z), f3 = bf2f(v.w);
    s += f0 * load1(a_src, h * C + c + 0, fb) + f1 * load1(a_src, h * C + c + 1, fb)
       + f2 * load1(a_src, h * C + c + 2, fb) + f3 * load1(a_src, h * C + c + 3, fb);
    d += f0 * load1(a_dst, h * C + c + 0, fb) + f1 * load1(a_dst, h * C + c + 1, fb)
       + f2 * load1(a_dst, h * C + c + 2, fb) + f3 * load1(a_dst, h * C + c + 3, fb);
  }
  asg[id] = s;
  adg[id] = d;
}

// ---------------- per-node softmax + aggregation (wave per node, bf16 h) ----

template <int H, int C, bool RELU, bool FINAL>
__global__ __launch_bounds__(256) void k_agg(const u16* __restrict__ hbuf,
                                             const float* __restrict__ asg,
                                             const float* __restrict__ adg,
                                             const int* __restrict__ rowptr,
                                             const int* __restrict__ srcs,
                                             const void* __restrict__ bias,
                                             const int* __restrict__ flags,
                                             void* __restrict__ outp, int n) {
  constexpr int HC = H * C;
  constexpr int CPL = (HC == 128) ? 2 : 1;
  __shared__ int lds_s[4][64];
  __shared__ float lds_a[4][64][H];
  int lane = threadIdx.x & 63;
  int w = threadIdx.x >> 6;
  int node = blockIdx.x * 4 + w;
  if (node >= n) return;
  bool fb = flags[1] != 0;
  int start = rowptr[node], end = rowptr[node + 1];
  if (end < start || end - start > TEDGE) { start = 0; end = 0; }

  float adh[H];
#pragma unroll
  for (int h = 0; h < H; ++h) adh[h] = adg[node * H + h];

  // pass 1: per-head max
  float mx[H];
#pragma unroll
  for (int h = 0; h < H; ++h) mx[h] = -1e30f;
  for (int e = start + lane; e < end; e += 64) {
    int s = srcs[e];
    float av[H];
    if (H == 4) { float4 t4 = *(const float4*)(asg + s * 4);
      av[0] = t4.x; av[1] = t4.y; av[H > 2 ? 2 : 0] = t4.z; av[H > 3 ? 3 : 0] = t4.w; }
    else if (H == 2) { float2 t2 = *(const float2*)(asg + s * 2); av[0] = t2.x; av[1] = t2.y; }
    else av[0] = asg[s];
#pragma unroll
    for (int h = 0; h < H; ++h)
      mx[h] = fmaxf(mx[h], lrelu(av[h] + adh[h]));
  }
#pragma unroll
  for (int off = 32; off >= 1; off >>= 1) {
#pragma unroll
    for (int h = 0; h < H; ++h) mx[h] = fmaxf(mx[h], __shfl_xor(mx[h], off));
  }

  // pass 2: denom
  float sm[H];
#pragma unroll
  for (int h = 0; h < H; ++h) sm[h] = 0.f;
  for (int e = start + lane; e < end; e += 64) {
    int s = srcs[e];
    float av[H];
    if (H == 4) { float4 t4 = *(const float4*)(asg + s * 4);
      av[0] = t4.x; av[1] = t4.y; av[H > 2 ? 2 : 0] = t4.z; av[H > 3 ? 3 : 0] = t4.w; }
    else if (H == 2) { float2 t2 = *(const float2*)(asg + s * 2); av[0] = t2.x; av[1] = t2.y; }
    else av[0] = asg[s];
#pragma unroll
    for (int h = 0; h < H; ++h)
      sm[h] += __expf(fminf(lrelu(av[h] + adh[h]) - mx[h], 60.f));
  }
#pragma unroll
  for (int off = 32; off >= 1; off >>= 1) {
#pragma unroll
    for (int h = 0; h < H; ++h) sm[h] += __shfl_xor(sm[h], off);
  }
  float inv[H];
#pragma unroll
  for (int h = 0; h < H; ++h) inv[h] = 1.f / (sm[h] + 1e-16f);

  int myhead;
  if (CPL == 2) myhead = lane >> 4;                 // 2 ch/lane, C=32
  else if (H == 2) myhead = lane >> 5;              // 1 ch/lane, C=32
  else myhead = 0;
  bool active = (CPL == 2) || (lane < HC);

  // pass 3: stage src+alpha in wave-private LDS, 4x-unrolled gather
  float accA0 = 0.f, accA1 = 0.f, accB0 = 0.f, accB1 = 0.f;
  for (int chunk = start; chunk < end; chunk += 64) {
    int e = chunk + lane;
    int s = 0;
    float aw[H];
#pragma unroll
    for (int h = 0; h < H; ++h) aw[h] = 0.f;
    if (e < end) {
      s = srcs[e];
      float av[H];
      if (H == 4) { float4 t4 = *(const float4*)(asg + s * 4);
        av[0] = t4.x; av[1] = t4.y; av[H > 2 ? 2 : 0] = t4.z; av[H > 3 ? 3 : 0] = t4.w; }
      else if (H == 2) { float2 t2 = *(const float2*)(asg + s * 2); av[0] = t2.x; av[1] = t2.y; }
      else av[0] = asg[s];
#pragma unroll
      for (int h = 0; h < H; ++h)
        aw[h] = __expf(fminf(lrelu(av[h] + adh[h]) - mx[h], 60.f)) * inv[h];
    }
    __builtin_amdgcn_wave_barrier();  // prior reads done before overwrite
    lds_s[w][lane] = s;
#pragma unroll
    for (int h = 0; h < H; ++h) lds_a[w][lane][h] = aw[h];
    __builtin_amdgcn_wave_barrier();

    int cn = min(64, end - chunk);
    for (int j = 0; j < cn; j += 4) {  // arrays zero-padded: overrun is harmless
      int s0 = lds_s[w][j + 0], s1 = lds_s[w][j + 1];
      int s2 = lds_s[w][j + 2], s3 = lds_s[w][j + 3];
      float A0 = lds_a[w][j + 0][myhead], A1 = lds_a[w][j + 1][myhead];
      float A2 = lds_a[w][j + 2][myhead], A3 = lds_a[w][j + 3][myhead];
      if (CPL == 2) {
        u32 w0 = *(const u32*)(hbuf + (size_t)s0 * HC + 2 * lane);
        u32 w1 = *(const u32*)(hbuf + (size_t)s1 * HC + 2 * lane);
        u32 w2 = *(const u32*)(hbuf + (size_t)s2 * HC + 2 * lane);
        u32 w3 = *(const u32*)(hbuf + (size_t)s3 * HC + 2 * lane);
        accA0 += A0 * bflo(w0); accA1 += A0 * bfhi(w0);
        accB0 += A1 * bflo(w1); accB1 += A1 * bfhi(w1);
        accA0 += A2 * bflo(w2); accA1 += A2 * bfhi(w2);
        accB0 += A3 * bflo(w3); accB1 += A3 * bfhi(w3);
      } else if (active) {
        float v0 = bf2f(hbuf[(size_t)s0 * HC + lane]);
        float v1 = bf2f(hbuf[(size_t)s1 * HC + lane]);
        float v2 = bf2f(hbuf[(size_t)s2 * HC + lane]);
        float v3 = bf2f(hbuf[(size_t)s3 * HC + lane]);
        accA0 += A0 * v0; accB0 += A1 * v1;
        accA0 += A2 * v2; accB0 += A3 * v3;
      }
    }
  }
  float acc0 = accA0 + accB0, acc1 = accA1 + accB1;

  // epilogue
  bool obf = FINAL ? fb : true;
  if (CPL == 2) {
    int c0 = 2 * lane;
    float v0 = acc0 + load1(bias, c0, fb);
    float v1 = acc1 + load1(bias, c0 + 1, fb);
    if (RELU) { v0 = fmaxf(v0, 0.f); v1 = fmaxf(v1, 0.f); }
    u32 wv = (u32)f2bf(v0) | ((u32)f2bf(v1) << 16);
    *(u32*)((u16*)outp + (size_t)node * HC + c0) = wv;
  } else if (active) {
    float v = acc0 + load1(bias, lane, fb);
    if (RELU) v = fmaxf(v, 0.f);
    if (obf) ((u16*)outp)[(size_t)node * HC + lane] = f2bf(v);
    else ((float*)outp)[(size_t)node * HC + lane] = v;
  }
}

// ---------------- launch ----------------

extern "C" void kernel_launch(void* const* d_in, const int* in_sizes, int n_in,
                              void* d_out, int out_size, void* d_ws, size_t ws_size,
                              hipStream_t stream) {
  const void* x   = d_in[0];
  const int* ei   = (const int*)d_in[1];
  const void* W1  = d_in[2];
  const void* as1 = d_in[3];
  const void* ad1 = d_in[4];
  const void* b1  = d_in[5];
  const void* W2  = d_in[6];
  const void* as2 = d_in[7];
  const void* ad2 = d_in[8];
  const void* b2  = d_in[9];
  const void* W3  = d_in[10];
  const void* as3 = d_in[11];
  const void* ad3 = d_in[12];
  const void* b3  = d_in[13];

  char* w = (char*)d_ws;
  auto alloc = [&](size_t bytes) {
    char* p = w;
    w += (bytes + 255) & ~(size_t)255;
    return p;
  };
  int* flags    = (int*)alloc(256);
  int* deg      = (int*)alloc((size_t)NODES * 4);
  int* cursor   = (int*)alloc((size_t)NODES * 4);
  int* rowptr   = (int*)alloc((size_t)(NODES + 1) * 4);
  int* srcs     = (int*)alloc((size_t)TEDGE * 4);
  float* asg    = (float*)alloc((size_t)NODES * 4 * 4);
  float* adg    = (float*)alloc((size_t)NODES * 4 * 4);
  u16* wt1      = (u16*)alloc((size_t)128 * 128 * 2);
  u16* wt2      = (u16*)alloc((size_t)64 * 128 * 2);
  u16* wt3      = (u16*)alloc((size_t)16 * 64 * 2);
  u16* hbuf     = (u16*)alloc((size_t)NODES * 128 * 2);
  u16* obuf     = (u16*)alloc((size_t)NODES * 128 * 2);

  // probes + deg zero + weight transpose + CSR build
  k_probe<<<(NODES + 255) / 256, 256, 0, stream>>>(ei, (const u16*)x, flags, deg);
  k_tw<<<100, 256, 0, stream>>>(W1, W2, W3, flags, wt1, wt2, wt3);
  k_hist<<<(TEDGE + 255) / 256, 256, 0, stream>>>(ei, flags, deg);
  k_scan<<<1, 1024, 0, stream>>>(deg, rowptr, cursor, NODES);
  k_scatter<<<(TEDGE + 255) / 256, 256, 0, stream>>>(ei, flags, cursor, srcs);

  int gblocks = (NODES + 63) / 64;
  // layer 1: 128 -> 4x32 concat, relu
  k_gmfma<128, 128, true><<<gblocks, 256, 0, stream>>>(x, wt1, hbuf, flags, NODES);
  k_attdot<4, 32><<<(NODES * 4 + 255) / 256, 256, 0, stream>>>(hbuf, as1, ad1, flags, asg, adg, NODES);
  k_agg<4, 32, true, false><<<(NODES + 3) / 4, 256, 0, stream>>>(hbuf, asg, adg, rowptr, srcs, b1, flags, obuf, NODES);
  // layer 2: 128 -> 2x32 concat, relu
  k_gmfma<128, 64, false><<<gblocks, 256, 0, stream>>>(obuf, wt2, hbuf, flags, NODES);
  k_attdot<2, 32><<<(NODES * 2 + 255) / 256, 256, 0, stream>>>(hbuf, as2, ad2, flags, asg, adg, NODES);
  k_agg<2, 32, true, false><<<(NODES + 3) / 4, 256, 0, stream>>>(hbuf, asg, adg, rowptr, srcs, b2, flags, obuf, NODES);
  // layer 3: 64 -> 1x16 mean(=identity), out dtype follows input dtype
  k_gmfma<64, 16, false><<<gblocks, 256, 0, stream>>>(obuf, wt3, hbuf, flags, NODES);
  k_attdot<1, 16><<<(NODES + 255) / 256, 256, 0, stream>>>(hbuf, as3, ad3, flags, asg, adg, NODES);
  k_agg<1, 16, false, true><<<(NODES + 3) / 4, 256, 0, stream>>>(hbuf, asg, adg, rowptr, srcs, b3, flags, d_out, NODES);
}

// Round 6
// 325.997 us; speedup vs baseline: 1.8268x; 1.2343x over previous
//
#include <hip/hip_runtime.h>
#include <hip/hip_bf16.h>
#include <stdint.h>

#define NODES 50000
#define NEDGE 800000
#define TEDGE (NEDGE + NODES)

typedef unsigned short u16;
typedef unsigned int u32;
typedef unsigned long long u64;
typedef short s16x8 __attribute__((ext_vector_type(8)));
typedef float f32x4 __attribute__((ext_vector_type(4)));

__device__ __forceinline__ float bf2f(u16 v) {
  return __uint_as_float(((u32)v) << 16);
}
__device__ __forceinline__ u16 f2bf(float f) {
  u32 u = __float_as_uint(f);
  u32 r = (u + 0x7FFFu + ((u >> 16) & 1u)) >> 16;
  return (u16)r;
}
__device__ __forceinline__ float lrelu(float x) {
  return (x > 0.f) ? x : 0.2f * x;
}
__device__ __forceinline__ int clampn(int v) {
  return ((u32)v < NODES) ? v : 0;
}
// fb = "external float arrays are bf16"; else plain f32
__device__ __forceinline__ float load1(const void* p, size_t i, bool fb) {
  return fb ? bf2f(((const u16*)p)[i]) : ((const float*)p)[i];
}
__device__ __forceinline__ float bflo(u32 w) { return __uint_as_float(w << 16); }
__device__ __forceinline__ float bfhi(u32 w) { return __uint_as_float(w & 0xFFFF0000u); }
// order-preserving float<->uint encoding for unsigned atomicMax
__device__ __forceinline__ u32 encf(float f) {
  u32 u = __float_as_uint(f);
  return (u & 0x80000000u) ? ~u : (u | 0x80000000u);
}
__device__ __forceinline__ float decf(u32 k) {
  u32 u = (k & 0x80000000u) ? (k & 0x7FFFFFFFu) : ~k;
  return __uint_as_float(u);
}

// ---------------- probes + deg/gm zero ----------------
// flags[0]: edge_index is int64; flags[1]: float arrays are bf16
// flags[8..31]: encoded per-head global maxes (3 layers)
__global__ __launch_bounds__(256) void k_probe(const int* __restrict__ ei,
                                               const u16* __restrict__ xs16,
                                               int* __restrict__ flags,
                                               int* __restrict__ deg) {
  int t = threadIdx.x;
  int g = blockIdx.x * 256 + t;
  if (g < NODES) deg[g] = 0;
  if (blockIdx.x == 0 && t >= 2 && t < 32) flags[t] = 0;
  if (blockIdx.x == 0 && t < 64) {
    int odd = 0, even = 0, big = 0;
#pragma unroll
    for (int k = 0; k < 4; ++k) {
      int idx = t + 64 * k;
      odd |= (ei[2 * idx + 1] != 0);
      even |= (ei[2 * idx] != 0);
      u32 ex = (xs16[2 * (t * 4 + k)] >> 7) & 0xFF;
      big += (ex >= 0x90);  // |v| >= 2^17: impossible for N(0,1) bf16
    }
    u64 bo = __ballot(odd);
    u64 be = __ballot(even);
#pragma unroll
    for (int off = 32; off >= 1; off >>= 1) big += __shfl_xor(big, off);
    if (t == 0) {
      flags[0] = (bo == 0ull && be != 0ull) ? 1 : 0;
      flags[1] = (big >= 8) ? 0 : 1;
    }
  }
}

// ---------------- W transpose: Wt[n][k] = W[k][n], bf16 out ----------------
__global__ __launch_bounds__(256) void k_tw(const void* __restrict__ W1,
                                            const void* __restrict__ W2,
                                            const void* __restrict__ W3,
                                            const int* __restrict__ flags,
                                            u16* __restrict__ wt1,
                                            u16* __restrict__ wt2,
                                            u16* __restrict__ wt3) {
  int id = blockIdx.x * 256 + threadIdx.x;
  bool fb = flags[1] != 0;
  if (id < 16384) {                       // W1: 128(K) x 128(N)
    int n = id >> 7, k = id & 127;
    wt1[n * 128 + k] = f2bf(load1(W1, (size_t)k * 128 + n, fb));
  } else if (id < 24576) {                // W2: 128(K) x 64(N)
    int r = id - 16384;
    int n = r >> 7, k = r & 127;
    wt2[n * 128 + k] = f2bf(load1(W2, (size_t)k * 64 + n, fb));
  } else if (id < 25600) {                // W3: 64(K) x 16(N)
    int r = id - 24576;
    int n = r >> 6, k = r & 63;
    wt3[n * 64 + k] = f2bf(load1(W3, (size_t)k * 16 + n, fb));
  }
}

// ---------------- CSR build ----------------
// hist: count degrees AND record each edge's rank within its dst row.

__global__ __launch_bounds__(256) void k_hist(const int* __restrict__ ei,
                                              const int* __restrict__ flags,
                                              int* deg, int* __restrict__ rankarr) {
  int e = blockIdx.x * 256 + threadIdx.x;
  if (e >= TEDGE) return;
  int d;
  if (e < NEDGE) {
    d = flags[0] ? ei[2 * (NEDGE + e)] : ei[NEDGE + e];
  } else {
    d = e - NEDGE;
  }
  rankarr[e] = atomicAdd(&deg[clampn(d)], 1);
}

__global__ __launch_bounds__(1024) void k_scan(const int* __restrict__ deg,
                                               int* __restrict__ rowptr, int n) {
  int t = threadIdx.x, lane = t & 63, w = t >> 6;
  __shared__ int swave[16], soff[17];
  int carry = 0;
  for (int base = 0; base < n; base += 4096) {
    int i0 = base + t * 4;
    int v[4];
#pragma unroll
    for (int j = 0; j < 4; j++) { int i = i0 + j; v[j] = (i < n) ? deg[i] : 0; }
    int local = v[0] + v[1] + v[2] + v[3];
    int x = local;
#pragma unroll
    for (int off = 1; off < 64; off <<= 1) {
      int y = __shfl_up(x, off);
      if (lane >= off) x += y;
    }
    if (lane == 63) swave[w] = x;
    __syncthreads();
    if (w == 0) {
      int wv = (lane < 16) ? swave[lane] : 0;
#pragma unroll
      for (int off = 1; off < 16; off <<= 1) {
        int y = __shfl_up(wv, off);
        if (lane >= off) wv += y;
      }
      if (lane < 16) soff[lane + 1] = wv;
      if (lane == 0) soff[0] = 0;
    }
    __syncthreads();
    int run = carry + soff[w] + (x - local);
#pragma unroll
    for (int j = 0; j < 4; j++) {
      int i = i0 + j;
      if (i < n) rowptr[i] = run;
      run += v[j];
    }
    carry += soff[16];
    __syncthreads();
  }
  if (t == 0) rowptr[n] = carry;
}

__global__ __launch_bounds__(256) void k_scatter(const int* __restrict__ ei,
                                                 const int* __restrict__ flags,
                                                 const int* __restrict__ rowptr,
                                                 const int* __restrict__ rankarr,
                                                 int* __restrict__ srcs) {
  int e = blockIdx.x * 256 + threadIdx.x;
  if (e >= TEDGE) return;
  int d, s;
  if (e < NEDGE) {
    if (flags[0]) { s = ei[2 * e]; d = ei[2 * (NEDGE + e)]; }
    else { s = ei[e]; d = ei[NEDGE + e]; }
  } else {
    s = e - NEDGE; d = s;
  }
  int pos = rowptr[clampn(d)] + rankarr[e];
  srcs[pos] = clampn(s);
}

// ---------------- MFMA GEMM: h[M,N] = x[M,K] @ W[K,N], bf16 in/out ----------
// Wt is pre-transposed [N][K]. 64 rows per block, wave w handles rows w*16..+15.
// Fragment maps (verified): A[m=lane&15][k=quad*8+j]; B[k=quad*8+j][n=lane&15];
// D[row=quad*4+reg][col=lane&15].

template <int K, int N, bool XEXT>
__global__ __launch_bounds__(256) void k_gmfma(const void* __restrict__ xin,
                                               const u16* __restrict__ wtg,
                                               u16* __restrict__ hout,
                                               const int* __restrict__ flags,
                                               int M) {
  constexpr int KP = K + 8;       // +8 bf16 pad: fragment reads 2-way only
  constexpr int NT = N / 16;
  constexpr int KG = K / 8;
  __shared__ u16 wlds[N * KP];
  __shared__ u16 xlds[64 * KP];
  int t = threadIdx.x;
  int row0 = blockIdx.x * 64;
  bool fb = flags[1] != 0;

  for (int i = t; i < N * KG; i += 256) {  // stage W^T (16B groups)
    int n = i / KG, kg = i % KG;
    *(uint4*)&wlds[n * KP + kg * 8] = *(const uint4*)(wtg + (size_t)n * K + kg * 8);
  }
  bool xbf = XEXT ? fb : true;
  for (int i = t; i < 64 * KG; i += 256) {  // stage x rows
    int r = i / KG, kg = i % KG;
    int grow = row0 + r;
    if (grow >= M) grow = M - 1;
    if (xbf) {
      *(uint4*)&xlds[r * KP + kg * 8] =
          *(const uint4*)((const u16*)xin + (size_t)grow * K + kg * 8);
    } else {
      const float* gp = (const float*)xin + (size_t)grow * K + kg * 8;
      float4 f0 = *(const float4*)gp, f1 = *(const float4*)(gp + 4);
      *(ushort4*)&xlds[r * KP + kg * 8] =
          make_ushort4(f2bf(f0.x), f2bf(f0.y), f2bf(f0.z), f2bf(f0.w));
      *(ushort4*)&xlds[r * KP + kg * 8 + 4] =
          make_ushort4(f2bf(f1.x), f2bf(f1.y), f2bf(f1.z), f2bf(f1.w));
    }
  }
  __syncthreads();

  int lane = t & 63, w = t >> 6;
  int lrow = lane & 15, quad = lane >> 4;
  f32x4 acc[NT];
#pragma unroll
  for (int nt = 0; nt < NT; ++nt) acc[nt] = (f32x4){0.f, 0.f, 0.f, 0.f};

  const u16* xbase = xlds + (w * 16 + lrow) * KP + quad * 8;
  const u16* wbase = wlds + lrow * KP + quad * 8;
#pragma unroll
  for (int ks = 0; ks < K / 32; ++ks) {
    s16x8 a = *(const s16x8*)(xbase + ks * 32);
#pragma unroll
    for (int nt = 0; nt < NT; ++nt) {
      s16x8 b = *(const s16x8*)(wbase + (size_t)nt * 16 * KP + ks * 32);
      acc[nt] = __builtin_amdgcn_mfma_f32_16x16x32_bf16(a, b, acc[nt], 0, 0, 0);
    }
  }

  int baserow = row0 + w * 16 + quad * 4;
#pragma unroll
  for (int nt = 0; nt < NT; ++nt) {
#pragma unroll
    for (int r = 0; r < 4; ++r) {
      int grow = baserow + r;
      if (grow < M)
        hout[(size_t)grow * N + nt * 16 + lrow] = f2bf(acc[nt][r]);
    }
  }
}

// ---------------- attention dots + global per-head max reduction ----------

template <int H, int C>
__global__ __launch_bounds__(256) void k_attdot(const u16* __restrict__ hbuf,
                                                const void* __restrict__ a_src,
                                                const void* __restrict__ a_dst,
                                                const int* __restrict__ flags,
                                                u32* __restrict__ gm,
                                                float* __restrict__ asg,
                                                float* __restrict__ adg, int n) {
  __shared__ u32 lm[2 * H];
  int t = threadIdx.x;
  if (t < 2 * H) lm[t] = 0;
  __syncthreads();
  int id = blockIdx.x * 256 + t;
  bool fb = flags[1] != 0;
  if (id < n * H) {
    int node = id / H, h = id % H;
    const u16* hp = hbuf + (size_t)node * (H * C) + h * C;
    float s = 0.f, d = 0.f;
#pragma unroll
    for (int c = 0; c < C; c += 4) {
      ushort4 v = *(const ushort4*)(hp + c);
      float f0 = bf2f(v.x), f1 = bf2f(v.y), f2 = bf2f(v.z), f3 = bf2f(v.w);
      s += f0 * load1(a_src, h * C + c + 0, fb) + f1 * load1(a_src, h * C + c + 1, fb)
         + f2 * load1(a_src, h * C + c + 2, fb) + f3 * load1(a_src, h * C + c + 3, fb);
      d += f0 * load1(a_dst, h * C + c + 0, fb) + f1 * load1(a_dst, h * C + c + 1, fb)
         + f2 * load1(a_dst, h * C + c + 2, fb) + f3 * load1(a_dst, h * C + c + 3, fb);
    }
    asg[id] = s;
    adg[id] = d;
    atomicMax(&lm[h], encf(s));
    atomicMax(&lm[H + h], encf(d));
  }
  __syncthreads();
  if (t < 2 * H) atomicMax(&gm[t], lm[t]);
}

// ---------------- fused softmax + aggregation (wave per node, one edge pass) --
// Softmax shift-invariance: alpha = exp(l - M)/sum exp(l - M) for ANY uniform
// M >= all logits (here global per-head bound from gm). Numerator and
// denominator accumulated in the same pass; divide at the end.
// Gather layout: L = HC/4 lanes per edge row (4 ch each, dwordx2), EPW = 64/L
// edges processed per wave-iteration, 2x unrolled.

template <int H, int C, bool RELU, bool FINAL>
__global__ __launch_bounds__(256) void k_agg(const u16* __restrict__ hbuf,
                                             const float* __restrict__ asg,
                                             const float* __restrict__ adg,
                                             const int* __restrict__ rowptr,
                                             const int* __restrict__ srcs,
                                             const void* __restrict__ bias,
                                             const int* __restrict__ flags,
                                             const u32* __restrict__ gm,
                                             void* __restrict__ outp, int n) {
  constexpr int HC = H * C;
  constexpr int L = HC / 4;     // lanes per edge row
  constexpr int EPW = 64 / L;   // edges per wave-iteration
  constexpr int ST = 2 * EPW;   // unrolled stride
  __shared__ int lds_s[4][64];
  __shared__ float lds_e[4][64][H];
  int lane = threadIdx.x & 63;
  int w = threadIdx.x >> 6;
  int node = blockIdx.x * 4 + w;
  if (node >= n) return;
  bool fb = flags[1] != 0;
  int start = rowptr[node], end = rowptr[node + 1];
  if (end < start || end - start > TEDGE) { start = 0; end = 0; }

  float adh[H], M[H];
#pragma unroll
  for (int h = 0; h < H; ++h) adh[h] = adg[node * H + h];
#pragma unroll
  for (int h = 0; h < H; ++h) M[h] = lrelu(decf(gm[h]) + decf(gm[H + h]));

  int sub = lane / L;
  int cl = lane & (L - 1);
  int ch0 = cl * 4;
  int myhead = ch0 / C;

  float den[H];
#pragma unroll
  for (int h = 0; h < H; ++h) den[h] = 0.f;
  float4 accA = make_float4(0.f, 0.f, 0.f, 0.f);
  float4 accB = make_float4(0.f, 0.f, 0.f, 0.f);

  for (int chunk = start; chunk < end; chunk += 64) {
    int e = chunk + lane;
    int s = 0;
    float ee[H];
#pragma unroll
    for (int h = 0; h < H; ++h) ee[h] = 0.f;
    if (e < end) {
      s = srcs[e];
      float av[H];
      if (H == 4) { float4 t4 = *(const float4*)(asg + s * 4);
        av[0] = t4.x; av[1] = t4.y; av[H > 2 ? 2 : 0] = t4.z; av[H > 3 ? 3 : 0] = t4.w; }
      else if (H == 2) { float2 t2 = *(const float2*)(asg + s * 2); av[0] = t2.x; av[1] = t2.y; }
      else av[0] = asg[s];
#pragma unroll
      for (int h = 0; h < H; ++h) {
        float x = __expf(lrelu(av[h] + adh[h]) - M[h]);  // arg <= 0 by bound
        ee[h] = x;
        den[h] += x;
      }
    }
    __builtin_amdgcn_wave_barrier();  // prior reads done before overwrite
    lds_s[w][lane] = s;
#pragma unroll
    for (int h = 0; h < H; ++h) lds_e[w][lane][h] = ee[h];
    __builtin_amdgcn_wave_barrier();

    int cn = min(64, end - chunk);
    for (int j = 0; j < cn; j += ST) {  // staged arrays zero-padded to 64
      int e0 = j + sub, e1 = j + EPW + sub;
      int s0 = lds_s[w][e0];
      float a0 = lds_e[w][e0][myhead];
      int s1 = lds_s[w][e1];
      float a1 = lds_e[w][e1][myhead];
      uint2 v0 = *(const uint2*)(hbuf + (size_t)s0 * HC + ch0);
      uint2 v1 = *(const uint2*)(hbuf + (size_t)s1 * HC + ch0);
      accA.x += a0 * bflo(v0.x); accA.y += a0 * bfhi(v0.x);
      accA.z += a0 * bflo(v0.y); accA.w += a0 * bfhi(v0.y);
      accB.x += a1 * bflo(v1.x); accB.y += a1 * bfhi(v1.x);
      accB.z += a1 * bflo(v1.y); accB.w += a1 * bfhi(v1.y);
    }
  }

  // wave-reduce denominators
#pragma unroll
  for (int m = 32; m >= 1; m >>= 1) {
#pragma unroll
    for (int h = 0; h < H; ++h) den[h] += __shfl_xor(den[h], m);
  }
  // cross-sub reduce the channel accumulators
  float4 t4 = make_float4(accA.x + accB.x, accA.y + accB.y,
                          accA.z + accB.z, accA.w + accB.w);
#pragma unroll
  for (int m = L; m < 64; m <<= 1) {
    t4.x += __shfl_xor(t4.x, m); t4.y += __shfl_xor(t4.y, m);
    t4.z += __shfl_xor(t4.z, m); t4.w += __shfl_xor(t4.w, m);
  }

  if (sub == 0) {
    float inv = 1.f / (den[myhead] + 1e-16f);
    float o0 = t4.x * inv + load1(bias, ch0 + 0, fb);
    float o1 = t4.y * inv + load1(bias, ch0 + 1, fb);
    float o2 = t4.z * inv + load1(bias, ch0 + 2, fb);
    float o3 = t4.w * inv + load1(bias, ch0 + 3, fb);
    if (RELU) {
      o0 = fmaxf(o0, 0.f); o1 = fmaxf(o1, 0.f);
      o2 = fmaxf(o2, 0.f); o3 = fmaxf(o3, 0.f);
    }
    bool obf = FINAL ? fb : true;
    if (obf) {
      uint2 pk;
      pk.x = (u32)f2bf(o0) | ((u32)f2bf(o1) << 16);
      pk.y = (u32)f2bf(o2) | ((u32)f2bf(o3) << 16);
      *(uint2*)((u16*)outp + (size_t)node * HC + ch0) = pk;
    } else {
      *(float4*)((float*)outp + (size_t)node * HC + ch0) =
          make_float4(o0, o1, o2, o3);
    }
  }
}

// ---------------- launch ----------------

extern "C" void kernel_launch(void* const* d_in, const int* in_sizes, int n_in,
                              void* d_out, int out_size, void* d_ws, size_t ws_size,
                              hipStream_t stream) {
  const void* x   = d_in[0];
  const int* ei   = (const int*)d_in[1];
  const void* W1  = d_in[2];
  const void* as1 = d_in[3];
  const void* ad1 = d_in[4];
  const void* b1  = d_in[5];
  const void* W2  = d_in[6];
  const void* as2 = d_in[7];
  const void* ad2 = d_in[8];
  const void* b2  = d_in[9];
  const void* W3  = d_in[10];
  const void* as3 = d_in[11];
  const void* ad3 = d_in[12];
  const void* b3  = d_in[13];

  char* w = (char*)d_ws;
  auto alloc = [&](size_t bytes) {
    char* p = w;
    w += (bytes + 255) & ~(size_t)255;
    return p;
  };
  int* flags    = (int*)alloc(256);
  int* deg      = (int*)alloc((size_t)NODES * 4);
  int* rowptr   = (int*)alloc((size_t)(NODES + 1) * 4);
  int* rankarr  = (int*)alloc((size_t)TEDGE * 4);
  int* srcs     = (int*)alloc((size_t)TEDGE * 4);
  float* asg    = (float*)alloc((size_t)NODES * 4 * 4);
  float* adg    = (float*)alloc((size_t)NODES * 4 * 4);
  u16* wt1      = (u16*)alloc((size_t)128 * 128 * 2);
  u16* wt2      = (u16*)alloc((size_t)64 * 128 * 2);
  u16* wt3      = (u16*)alloc((size_t)16 * 64 * 2);
  u16* hbuf     = (u16*)alloc((size_t)NODES * 128 * 2);
  u16* obuf     = (u16*)alloc((size_t)NODES * 128 * 2);

  u32* gm1 = (u32*)(flags + 8);
  u32* gm2 = (u32*)(flags + 16);
  u32* gm3 = (u32*)(flags + 24);

  // probes + zeroing + weight transpose + CSR build
  k_probe<<<(NODES + 255) / 256, 256, 0, stream>>>(ei, (const u16*)x, flags, deg);
  k_tw<<<100, 256, 0, stream>>>(W1, W2, W3, flags, wt1, wt2, wt3);
  k_hist<<<(TEDGE + 255) / 256, 256, 0, stream>>>(ei, flags, deg, rankarr);
  k_scan<<<1, 1024, 0, stream>>>(deg, rowptr, NODES);
  k_scatter<<<(TEDGE + 255) / 256, 256, 0, stream>>>(ei, flags, rowptr, rankarr, srcs);

  int gblocks = (NODES + 63) / 64;
  // layer 1: 128 -> 4x32 concat, relu
  k_gmfma<128, 128, true><<<gblocks, 256, 0, stream>>>(x, wt1, hbuf, flags, NODES);
  k_attdot<4, 32><<<(NODES * 4 + 255) / 256, 256, 0, stream>>>(hbuf, as1, ad1, flags, gm1, asg, adg, NODES);
  k_agg<4, 32, true, false><<<(NODES + 3) / 4, 256, 0, stream>>>(hbuf, asg, adg, rowptr, srcs, b1, flags, gm1, obuf, NODES);
  // layer 2: 128 -> 2x32 concat, relu
  k_gmfma<128, 64, false><<<gblocks, 256, 0, stream>>>(obuf, wt2, hbuf, flags, NODES);
  k_attdot<2, 32><<<(NODES * 2 + 255) / 256, 256, 0, stream>>>(hbuf, as2, ad2, flags, gm2, asg, adg, NODES);
  k_agg<2, 32, true, false><<<(NODES + 3) / 4, 256, 0, stream>>>(hbuf, asg, adg, rowptr, srcs, b2, flags, gm2, obuf, NODES);
  // layer 3: 64 -> 1x16 mean(=identity), out dtype follows input dtype
  k_gmfma<64, 16, false><<<gblocks, 256, 0, stream>>>(obuf, wt3, hbuf, flags, NODES);
  k_attdot<1, 16><<<(NODES + 255) / 256, 256, 0, stream>>>(hbuf, as3, ad3, flags, gm3, asg, adg, NODES);
  k_agg<1, 16, false, true><<<(NODES + 3) / 4, 256, 0, stream>>>(hbuf, asg, adg, rowptr, srcs, b3, flags, gm3, d_out, NODES);
}